// Round 1
// baseline (261.798 us; speedup 1.0000x reference)
//
#include <hip/hip_runtime.h>
#include <hip/hip_bf16.h>
#include <cstdint>

#define N_PROT 19000
#define N_DRUGS 4200
#define BATCH 8192
#define D0 1024
#define D1 512
#define D2 128
#define NROWS (2 * BATCH)  // 16384 MLP rows (side-major: r = s*8192 + i)

typedef __bf16 bf16_t;
typedef __bf16 bf16x8 __attribute__((ext_vector_type(8)));
typedef __bf16 bf16x4 __attribute__((ext_vector_type(4)));
typedef float f32x4 __attribute__((ext_vector_type(4)));

// ---------------------------------------------------------------------------
// Kernel 1: per-drug sparse row-sum of W0.
// table is binary (~38 nonzeros of 19000). h0[d][:] = sum_{p: table[d][p]!=0} W0[p][:]
// One block per drug: scan row into LDS index list, then accumulate W0 rows
// coalesced (thread t owns columns 4t..4t+3).
// ---------------------------------------------------------------------------
__global__ __launch_bounds__(256) void k_build_h0(
    const float* __restrict__ table, const float* __restrict__ W0,
    float* __restrict__ h0)
{
  __shared__ int s_idx[512];
  __shared__ int s_cnt;
  const int d = blockIdx.x;
  if (threadIdx.x == 0) s_cnt = 0;
  __syncthreads();

  const float4* row = reinterpret_cast<const float4*>(table + (size_t)d * N_PROT);
  for (int q = threadIdx.x; q < N_PROT / 4; q += 256) {  // 19000 = 4*4750
    float4 v = row[q];
    if (v.x != 0.f) { int k = atomicAdd(&s_cnt, 1); if (k < 512) s_idx[k] = 4 * q + 0; }
    if (v.y != 0.f) { int k = atomicAdd(&s_cnt, 1); if (k < 512) s_idx[k] = 4 * q + 1; }
    if (v.z != 0.f) { int k = atomicAdd(&s_cnt, 1); if (k < 512) s_idx[k] = 4 * q + 2; }
    if (v.w != 0.f) { int k = atomicAdd(&s_cnt, 1); if (k < 512) s_idx[k] = 4 * q + 3; }
  }
  __syncthreads();
  const int nnz = min(s_cnt, 512);  // Binomial(19000,0.002): mean 38, 512 is unreachable

  const int j4 = threadIdx.x * 4;  // 256*4 = 1024 columns
  float4 acc = make_float4(0.f, 0.f, 0.f, 0.f);
  for (int t = 0; t < nnz; ++t) {
    const int p = s_idx[t];
    float4 w = *reinterpret_cast<const float4*>(W0 + (size_t)p * D0 + j4);
    acc.x += w.x; acc.y += w.y; acc.z += w.z; acc.w += w.w;
  }
  *reinterpret_cast<float4*>(h0 + (size_t)d * D0 + j4) = acc;
}

// ---------------------------------------------------------------------------
// Kernel 2: W1 (1024x512) -> W1T bf16 (512x1024); W2 (512x128) -> W2T bf16 (128x512)
// so GEMM B-fragments read 8 contiguous bf16 along K.
// ---------------------------------------------------------------------------
__global__ __launch_bounds__(256) void k_convert_w(
    const float* __restrict__ W1, const float* __restrict__ W2,
    bf16_t* __restrict__ W1T, bf16_t* __restrict__ W2T)
{
  const int idx = blockIdx.x * 256 + threadIdx.x;
  if (idx < D0 * D1) {                       // idx = n*D0 + k
    const int n = idx / D0, k = idx % D0;
    W1T[idx] = (bf16_t)W1[(size_t)k * D1 + n];
  } else {
    const int j = idx - D0 * D1;             // j = n*D1 + k
    if (j < D1 * D2) {
      const int n = j / D1, k = j % D1;
      W2T[j] = (bf16_t)W2[(size_t)k * D2 + n];
    }
  }
}

// ---------------------------------------------------------------------------
// Kernel 3: H[r][:] = relu(h0[drug(r)] + c(r)*W0_last + b0), bf16.
// r = s*8192 + i; drug = pairs[i][s]; c = conc[i][1+s].
// ---------------------------------------------------------------------------
__global__ __launch_bounds__(256) void k_build_H(
    const float* __restrict__ h0, const int* __restrict__ pairs,
    const float* __restrict__ conc, const float* __restrict__ W0last,
    const float* __restrict__ b0, bf16_t* __restrict__ H)
{
  const int r = blockIdx.x;
  const int s = r >> 13;
  const int i = r & (BATCH - 1);
  const int drug = pairs[2 * i + s];
  const float c = conc[3 * i + 1 + s];

  const int j = threadIdx.x * 4;
  float4 hv = *reinterpret_cast<const float4*>(h0 + (size_t)drug * D0 + j);
  float4 wl = *reinterpret_cast<const float4*>(W0last + j);
  float4 bv = *reinterpret_cast<const float4*>(b0 + j);
  bf16x4 o;
  o[0] = (bf16_t)fmaxf(hv.x + c * wl.x + bv.x, 0.f);
  o[1] = (bf16_t)fmaxf(hv.y + c * wl.y + bv.y, 0.f);
  o[2] = (bf16_t)fmaxf(hv.z + c * wl.z + bv.z, 0.f);
  o[3] = (bf16_t)fmaxf(hv.w + c * wl.w + bv.w, 0.f);
  *reinterpret_cast<bf16x4*>(H + (size_t)r * D0 + j) = o;
}

// ---------------------------------------------------------------------------
// GEMM: C[M x N] = op(A[M x K] @ B[K x N] + bias), B given transposed (N x K).
// Block tile 128x128, 4 waves in 2x2, each wave 64x64 via 4x4 MFMA fragments
// of v_mfma_f32_16x16x32_bf16. Direct-from-global operand loads (B is L2-hot).
// A-frag: lane l -> A[row0+m*16+(l&15)][k0+8*(l>>4)+v]  (16B contiguous)
// B-frag: lane l -> BT[col0+n*16+(l&15)][k0+8*(l>>4)+v] (16B contiguous)
// C/D:    lane l, reg r -> row=4*(l>>4)+r, col=(l&15)    [guide §3, m89-verified]
// ---------------------------------------------------------------------------
template <int K, int N, bool RELU, typename OUT_T>
__global__ __launch_bounds__(256) void k_gemm(
    const bf16_t* __restrict__ A, const bf16_t* __restrict__ BT,
    const float* __restrict__ bias, OUT_T* __restrict__ C)
{
  const int wid = threadIdx.x >> 6;
  const int lane = threadIdx.x & 63;
  const int wr = wid >> 1, wc = wid & 1;
  const int row0 = blockIdx.x * 128 + wr * 64;
  const int col0 = blockIdx.y * 128 + wc * 64;
  const int fr = lane & 15;
  const int fk = (lane >> 4) * 8;

  f32x4 acc[4][4] = {};
  for (int k0 = 0; k0 < K; k0 += 32) {
    bf16x8 a[4], b[4];
#pragma unroll
    for (int m = 0; m < 4; ++m)
      a[m] = *reinterpret_cast<const bf16x8*>(A + (size_t)(row0 + m * 16 + fr) * K + k0 + fk);
#pragma unroll
    for (int n = 0; n < 4; ++n)
      b[n] = *reinterpret_cast<const bf16x8*>(BT + (size_t)(col0 + n * 16 + fr) * K + k0 + fk);
#pragma unroll
    for (int m = 0; m < 4; ++m)
#pragma unroll
      for (int n = 0; n < 4; ++n)
        acc[m][n] = __builtin_amdgcn_mfma_f32_16x16x32_bf16(a[m], b[n], acc[m][n], 0, 0, 0);
  }

  const int cr = (lane >> 4) * 4;
  const int cc = lane & 15;
#pragma unroll
  for (int m = 0; m < 4; ++m)
#pragma unroll
    for (int n = 0; n < 4; ++n) {
      const int col = col0 + n * 16 + cc;
      const float bb = bias[col];
#pragma unroll
      for (int r = 0; r < 4; ++r) {
        float v = acc[m][n][r] + bb;
        if (RELU) v = fmaxf(v, 0.f);
        C[(size_t)(row0 + m * 16 + cr + r) * N + col] = (OUT_T)v;
      }
    }
}

// ---------------------------------------------------------------------------
// Kernel 6: out[i] = dot(Z[i], Z[8192+i]) over 128 f32.
// ---------------------------------------------------------------------------
__global__ __launch_bounds__(256) void k_dot(
    const float* __restrict__ Z, float* __restrict__ out)
{
  const int i = blockIdx.x * 256 + threadIdx.x;
  const float4* z1 = reinterpret_cast<const float4*>(Z + (size_t)i * D2);
  const float4* z2 = reinterpret_cast<const float4*>(Z + (size_t)(BATCH + i) * D2);
  float s = 0.f;
#pragma unroll
  for (int k = 0; k < D2 / 4; ++k) {
    float4 a = z1[k], b = z2[k];
    s += a.x * b.x + a.y * b.y + a.z * b.z + a.w * b.w;
  }
  out[i] = s;
}

extern "C" void kernel_launch(void* const* d_in, const int* in_sizes, int n_in,
                              void* d_out, int out_size, void* d_ws, size_t ws_size,
                              hipStream_t stream) {
  const float* table = (const float*)d_in[0];
  const int*   pairs = (const int*)d_in[1];
  const float* conc  = (const float*)d_in[2];
  const float* W0    = (const float*)d_in[3];
  const float* b0    = (const float*)d_in[4];
  const float* W1    = (const float*)d_in[5];
  const float* b1    = (const float*)d_in[6];
  const float* W2    = (const float*)d_in[7];
  const float* b2    = (const float*)d_in[8];
  float* out = (float*)d_out;

  // Workspace layout (all 16B-aligned; total ~77.1 MB)
  char* ws = (char*)d_ws;
  float*  h0  = (float*)ws;  ws += (size_t)N_DRUGS * D0 * sizeof(float);   // 17.2 MB
  bf16_t* W1T = (bf16_t*)ws; ws += (size_t)D1 * D0 * sizeof(bf16_t);       //  1.0 MB
  bf16_t* W2T = (bf16_t*)ws; ws += (size_t)D2 * D1 * sizeof(bf16_t);       //  0.13 MB
  bf16_t* H   = (bf16_t*)ws; ws += (size_t)NROWS * D0 * sizeof(bf16_t);    // 33.6 MB
  bf16_t* H1  = (bf16_t*)ws; ws += (size_t)NROWS * D1 * sizeof(bf16_t);    // 16.8 MB
  float*  Z   = (float*)ws;  ws += (size_t)NROWS * D2 * sizeof(float);     //  8.4 MB

  k_build_h0<<<N_DRUGS, 256, 0, stream>>>(table, W0, h0);
  k_convert_w<<<(D0 * D1 + D1 * D2 + 255) / 256, 256, 0, stream>>>(W1, W2, W1T, W2T);
  k_build_H<<<NROWS, 256, 0, stream>>>(h0, pairs, conc, W0 + (size_t)N_PROT * D0, b0, H);
  k_gemm<D0, D1, true,  bf16_t><<<dim3(NROWS / 128, D1 / 128), 256, 0, stream>>>(H, W1T, b1, H1);
  k_gemm<D1, D2, false, float ><<<dim3(NROWS / 128, D2 / 128), 256, 0, stream>>>(H1, W2T, b2, Z);
  k_dot<<<BATCH / 256, 256, 0, stream>>>(Z, out);
}